// Round 11
// baseline (447.502 us; speedup 1.0000x reference)
//
#include <hip/hip_runtime.h>
#include <hip/hip_fp16.h>

// VGAE on GCN: N=50000, E=1.6M, IN=256, HIDDEN=128, OUT=64.
// Round 21: direct global-atomic CSR build (hist -> 2-level scan -> scatter)
// replacing the 2-kernel bucket/binning pipeline (LDS-atomic-heavy, scattered
// pairs RMW round-trip, ~2x the work). CSR is now exactly contiguous (no CAP
// padding): rs[n+1]==re[n] globally, ssrc = E u16 exactly.
// Gather/GEMM kernels kept verbatim from R20 (pipelined MFMA-gather,
// XCD-pinned quarters, u16 ssrc in LDS, counted vmcnt/lgkmcnt).

#define IN_DIM 256
#define F1 128   // HIDDEN
#define F2 64    // OUT
#define QF 32    // features per quarter (F1/4)
#define SIDW 1024     // per-wave LDS ssrc capacity (u16)
#define SBLK 512      // u16 per prologue bulk-load block

typedef _Float16 f16x8 __attribute__((ext_vector_type(8)));
typedef _Float16 f16x4 __attribute__((ext_vector_type(4)));
typedef float f32x4 __attribute__((ext_vector_type(4)));

static inline int cdiv_i(int a, int b) { return (a + b - 1) / b; }

__device__ static inline uint32_t lds_addr(const void* p) {
    return (uint32_t)(size_t)(const __attribute__((address_space(3))) void*)p;
}

// ---- weight prep: fragment-ordered fp16 buffers ----
__global__ void k_prep_frags(const float* __restrict__ W1,
                             const float* __restrict__ Wmu,
                             const float* __restrict__ Wls,
                             __half* __restrict__ W1frag,
                             __half* __restrict__ Wcfrag) {
    int t = blockIdx.x * blockDim.x + threadIdx.x;
    if (t < 8 * 8 * 64) {
        int lane = t & 63, nt = (t >> 6) & 7, ks = t >> 9;
        int k0 = ks * 32 + ((lane >> 4) << 3);
        int n = nt * 16 + (lane & 15);
#pragma unroll
        for (int j = 0; j < 8; ++j)
            W1frag[(size_t)t * 8 + j] = __float2half(W1[(k0 + j) * F1 + n]);
    } else if (t < 8 * 8 * 64 + 4 * 8 * 64) {
        int u = t - 8 * 8 * 64;
        int lane = u & 63, nt = (u >> 6) & 7, ks = u >> 9;
        int k0 = ks * 32 + ((lane >> 4) << 3);
        int c = nt * 16 + (lane & 15);
        const float* W = (c < F2) ? (Wmu + c) : (Wls + (c - F2));
#pragma unroll
        for (int j = 0; j < 8; ++j)
            Wcfrag[(size_t)u * 8 + j] = __float2half(W[(k0 + j) * F2]);
    }
}

// ---- CSR build, direct: histogram -> 2-level scan -> finalize -> scatter ----
__global__ __launch_bounds__(512) void k_hist(const int* __restrict__ dst,
                                              int* __restrict__ cnt, int E) {
    const int e0 = blockIdx.x * 4096 + threadIdx.x;
#pragma unroll
    for (int i = 0; i < 8; ++i) {
        int e = e0 + i * 512;
        if (e < E) atomicAdd(&cnt[dst[e]], 1);
    }
}

__global__ __launch_bounds__(1024) void k_scan1(const int* __restrict__ cnt,
                                                int* __restrict__ rs,
                                                int* __restrict__ bsum, int N) {
    __shared__ int s[1024];
    const int t = threadIdx.x;
    const int n = blockIdx.x * 1024 + t;
    int v = (n < N) ? cnt[n] : 0;
    s[t] = v;
    __syncthreads();
    for (int o = 1; o < 1024; o <<= 1) {
        int a = (t >= o) ? s[t - o] : 0;
        __syncthreads();
        s[t] += a;
        __syncthreads();
    }
    if (n < N) rs[n] = s[t] - v;           // tile-exclusive
    if (t == 1023) bsum[blockIdx.x] = s[1023];
}

__global__ __launch_bounds__(64) void k_scan2(int* __restrict__ bsum, int nb) {
    __shared__ int s[64];
    const int t = threadIdx.x;
    int v = (t < nb) ? bsum[t] : 0;
    s[t] = v;
    __syncthreads();
    for (int o = 1; o < 64; o <<= 1) {
        int a = (t >= o) ? s[t - o] : 0;
        __syncthreads();
        s[t] += a;
        __syncthreads();
    }
    if (t < nb) bsum[t] = s[t] - v;        // exclusive block offsets, in place
}

__global__ __launch_bounds__(1024) void k_fin(const int* __restrict__ cnt,
                                              const int* __restrict__ bsum,
                                              int* __restrict__ rs,
                                              int* __restrict__ re,
                                              int* __restrict__ cur,
                                              float* __restrict__ dinv, int N) {
    const int n = blockIdx.x * 1024 + threadIdx.x;
    if (n >= N) return;
    const int base = rs[n] + bsum[blockIdx.x];
    const int c = cnt[n];
    rs[n] = base;
    re[n] = base + c;
    cur[n] = base;
    dinv[n] = rsqrtf((float)c + 1.0f);     // +1 self-loop
}

__global__ __launch_bounds__(512) void k_scatter(const int* __restrict__ src,
                                                 const int* __restrict__ dst,
                                                 int* __restrict__ cur,
                                                 ushort* __restrict__ ssrc, int E) {
    const int e0 = blockIdx.x * 4096 + threadIdx.x;
#pragma unroll
    for (int i = 0; i < 8; ++i) {
        int e = e0 + i * 512;
        if (e < E) {
            int p = atomicAdd(&cur[dst[e]], 1);
            ssrc[p] = (ushort)src[e];
        }
    }
}

// ---- GEMM1 MFMA: tq[4][M][32] = fp16( dinv[m] * (x[M,256] @ W1)[m] ) ----
__global__ __launch_bounds__(256) void k_gemm1_mfma(const float* __restrict__ x,
                                                    const __half* __restrict__ W1frag,
                                                    const float* __restrict__ dinv,
                                                    __half* __restrict__ C, int M) {
    const int wave = threadIdx.x >> 6;
    const int lane = threadIdx.x & 63;
    const int m0 = blockIdx.x * 64 + wave * 16;
    if (m0 >= M) return;
    const int q = lane >> 4;
    const int arow = m0 + (lane & 15);
    f32x4 acc[8] = {};
#pragma unroll
    for (int ks = 0; ks < 8; ++ks) {
        const float* ap = x + (size_t)arow * IN_DIM + ks * 32 + q * 8;
        f32x4 f0 = *(const f32x4*)(ap);
        f32x4 f1 = *(const f32x4*)(ap + 4);
        f16x8 a = { (_Float16)f0.x, (_Float16)f0.y, (_Float16)f0.z, (_Float16)f0.w,
                    (_Float16)f1.x, (_Float16)f1.y, (_Float16)f1.z, (_Float16)f1.w };
        const __half* bbase = W1frag + ((size_t)(ks * 8) * 64 + lane) * 8;
#pragma unroll
        for (int nt = 0; nt < 8; ++nt) {
            f16x8 bfrag = *(const f16x8*)(bbase + (size_t)nt * 64 * 8);
            acc[nt] = __builtin_amdgcn_mfma_f32_16x16x32_f16(a, bfrag, acc[nt], 0, 0, 0);
        }
    }
    float dv[4];
#pragma unroll
    for (int r = 0; r < 4; ++r) dv[r] = dinv[m0 + q * 4 + r];
#pragma unroll
    for (int nt = 0; nt < 8; ++nt) {
        int col = nt * 16 + (lane & 15);
        __half* cq = C + (size_t)(col >> 5) * M * QF + (col & 31);
#pragma unroll
        for (int r = 0; r < 4; ++r)
            cq[(size_t)(m0 + q * 4 + r) * QF] = __float2half(acc[nt][r] * dv[r]);
    }
}

// ---- GEMM2 MFMA: t2q[4][M][32] = fp16( dinv[m] * (h[M,128] @ Wcat)[m] ) ----
__global__ __launch_bounds__(256) void k_gemm2_mfma(const __half* __restrict__ A,
                                                    const __half* __restrict__ Wcfrag,
                                                    const float* __restrict__ dinv,
                                                    __half* __restrict__ C, int M) {
    const int wave = threadIdx.x >> 6;
    const int lane = threadIdx.x & 63;
    const int m0 = blockIdx.x * 64 + wave * 16;
    if (m0 >= M) return;
    const int q = lane >> 4;
    const int arow = m0 + (lane & 15);
    f32x4 acc[8] = {};
#pragma unroll
    for (int ks = 0; ks < 4; ++ks) {
        f16x8 a = *(const f16x8*)(A + (size_t)ks * M * QF + (size_t)arow * QF + q * 8);
        const __half* bbase = Wcfrag + ((size_t)(ks * 8) * 64 + lane) * 8;
#pragma unroll
        for (int nt = 0; nt < 8; ++nt) {
            f16x8 bfrag = *(const f16x8*)(bbase + (size_t)nt * 64 * 8);
            acc[nt] = __builtin_amdgcn_mfma_f32_16x16x32_f16(a, bfrag, acc[nt], 0, 0, 0);
        }
    }
    float dv[4];
#pragma unroll
    for (int r = 0; r < 4; ++r) dv[r] = dinv[m0 + q * 4 + r];
#pragma unroll
    for (int nt = 0; nt < 8; ++nt) {
        int col = nt * 16 + (lane & 15);
        __half* cq = C + (size_t)(col >> 5) * M * QF + (col & 31);
#pragma unroll
        for (int r = 0; r < 4; ++r)
            cq[(size_t)(m0 + q * 4 + r) * QF] = __float2half(acc[nt][r] * dv[r]);
    }
}

#define GLDS(GP, LP)                                                           \
    __builtin_amdgcn_global_load_lds(                                          \
        (const __attribute__((address_space(1))) void*)(GP),                   \
        (__attribute__((address_space(3))) void*)(LP), 16, 0, 0)

// ---- pipelined body: MFMA chunk C_ (regs C0..C3), read chunk C_+1 into
// N0..N3, issue stage C_+3 (sv SIA/SIB), load sv for C_+4 into SOA/SOB. ----
#define BODY(C_, C0, C1, C2, C3, N0, N1, N2, N3, SIA, SIB, SOA, SOB)           \
    {                                                                          \
        asm volatile("s_waitcnt lgkmcnt(4)" ::: "memory");                     \
        __builtin_amdgcn_sched_barrier(0);                                     \
        const __half* gA_ = tq + (size_t)(SIA) * QF + b8;                      \
        const __half* gB_ = tq + (size_t)(SIB) * QF + b8;                      \
        __half* LB_ = stg + ((((C_) + 3) & 3) << 10);                          \
        GLDS(gA_, LB_);                                                        \
        GLDS(gB_, LB_ + 512);                                                  \
        asm volatile("s_waitcnt vmcnt(4)" ::: "memory");                       \
        const uint32_t sva_ = sbb + 2u * (uint32_t)min(                        \
            ofs + ((C_) + 4) * 32 + e4, SIDW - 17);                            \
        const uint32_t tra_ = vaBase + ((uint32_t)(((C_) + 1) & 3) << 11);     \
        asm volatile(                                                          \
            "ds_read_u16 %0, %6\n\t"                                           \
            "ds_read_u16 %1, %6 offset:32\n\t"                                 \
            "ds_read_b64_tr_b16 %2, %7 offset:0\n\t"                           \
            "ds_read_b64_tr_b16 %3, %7 offset:1024\n\t"                        \
            "ds_read_b64_tr_b16 %4, %7 offset:32\n\t"                          \
            "ds_read_b64_tr_b16 %5, %7 offset:1056"                            \
            : "=&v"(SOA), "=&v"(SOB), "=&v"(N0), "=&v"(N1), "=&v"(N2),         \
              "=&v"(N3)                                                        \
            : "v"(sva_), "v"(tra_) : "memory");                                \
        const int eb_ = ebase + (C_) * 32;                                     \
        f16x8 af_;                                                             \
        _Pragma("unroll")                                                      \
        for (int j = 0; j < 8; ++j) {                                          \
            int m_ = eb_ + (j & 3) + ((j >> 2) << 4);                          \
            af_[j] = ((unsigned)m_ < dd) ? (_Float16)1.0f : (_Float16)0.0f;    \
        }                                                                      \
        asm volatile("s_waitcnt lgkmcnt(6)" ::: "memory");                     \
        __builtin_amdgcn_sched_barrier(0);                                     \
        f16x8 bf0_, bf1_;                                                      \
        _Pragma("unroll")                                                      \
        for (int j = 0; j < 4; ++j) {                                          \
            bf0_[j] = (C0)[j]; bf0_[j + 4] = (C1)[j];                          \
            bf1_[j] = (C2)[j]; bf1_[j + 4] = (C3)[j];                          \
        }                                                                      \
        acc0 = __builtin_amdgcn_mfma_f32_16x16x32_f16(af_, bf0_, acc0, 0, 0, 0); \
        acc1 = __builtin_amdgcn_mfma_f32_16x16x32_f16(af_, bf1_, acc1, 0, 0, 0); \
    }

// ---- grouped MFMA gather: wave = (16-node group, quarter), XCD-pinned ----
template<bool FIRST>
__global__ __launch_bounds__(256) void k_gather_mfma(
        const int* __restrict__ rs, const int* __restrict__ re,
        const ushort* __restrict__ ssrc, const float* __restrict__ dinv,
        const __half* __restrict__ t,
        const float* __restrict__ bA, const float* __restrict__ bB,
        __half* __restrict__ h, float* __restrict__ out,
        int N, int NG) {
    __shared__ __align__(16) __half  smem[4][4][1024];  // stage ring 4x2KB/wave
    __shared__ __align__(16) ushort  sidx[4][SIDW];     // ssrc 2KB/wave
    const int wave = threadIdx.x >> 6;
    const int lane = threadIdx.x & 63;
    const int x = blockIdx.x & 7;          // XCD slot (round-robin dispatch)
    const int q = x >> 1;                  // quarter pinned to XCD pair
    const int g = (((blockIdx.x >> 3) << 1) + (x & 1)) * 4 + wave;
    if (g >= NG) return;
    const int nb = g << 4;                 // first node of group
    const int e4 = lane >> 2;              // edge-in-halfchunk 0..15 (staging)
    const int b8 = (lane & 3) * 8;         // f16 offset of 16B quarter-row part
    const int col = lane & 15;
    const __half* tq = t + (size_t)q * N * QF;
    __half* stg = &smem[wave][0][0];
    ushort* sb = &sidx[wave][0];
    const uint32_t sbb = lds_addr(sb);
    const int o0 = rs[nb + col];           // node (=A row) col's edge range
    const int o1 = re[nb + col];
    const int gs = rs[nb];                 // group edge range (contiguous CSR)
    const int ge = re[nb + 15];
    const int ne = ge - gs;
    const int nc = (ne + 31) >> 5;
    const int m0 = (lane >> 4) << 2;       // A k->edge permutation base
    const int ebase = gs + m0 - o0;
    const unsigned dd = (unsigned)(o1 - o0);
    // tr-read addr, linear edge-major [32][32] (R18-verified):
    const uint32_t voff = 256u * (uint32_t)(lane >> 4)
                        + 64u * (uint32_t)((lane >> 2) & 3)
                        + 8u * (uint32_t)(lane & 3);
    const uint32_t vaBase = lds_addr(stg) + voff;
    f32x4 acc0 = {}, acc1 = {};

    const int gsa = gs & ~7;               // 16B-aligned prologue start (u16)
    const int ofs = gs - gsa;

    if (nc > 0) {
        // prologue: bulk ssrc -> LDS (512 u16 = 1KB per block instr)
        const int nblk = min((ofs + ne + SBLK - 1) / SBLK, SIDW / SBLK);
        for (int b = 0; b < nblk; ++b)
            GLDS(ssrc + gsa + b * SBLK + lane * 8, sb + b * SBLK);
        asm volatile("s_waitcnt vmcnt(0)" ::: "memory");   // ssrc resident
        // stages 0..2 (sv via C++ LDS reads; compiler-waited, queue empties)
#pragma unroll
        for (int p = 0; p < 3; ++p) {
            const int ia = min(ofs + p * 32 + e4, SIDW - 17);
            const int sA = sb[ia], sB = sb[ia + 16];
            __half* LB = stg + (p << 10);
            GLDS(tq + (size_t)sA * QF + b8, LB);
            GLDS(tq + (size_t)sB * QF + b8, LB + 512);
        }
        // initial asm: sv(3) + tr-read chunk 0  [queue: sv2 + tr4]
        uint32_t sv1A, sv1B, sv2A, sv2B;
        f16x4 RA0, RA1, RA2, RA3, RB0, RB1, RB2, RB3;
        {
            const uint32_t sva_ = sbb + 2u * (uint32_t)min(ofs + 96 + e4, SIDW - 17);
            asm volatile(
                "ds_read_u16 %0, %6\n\t"
                "ds_read_u16 %1, %6 offset:32\n\t"
                "ds_read_b64_tr_b16 %2, %7 offset:0\n\t"
                "ds_read_b64_tr_b16 %3, %7 offset:1024\n\t"
                "ds_read_b64_tr_b16 %4, %7 offset:32\n\t"
                "ds_read_b64_tr_b16 %5, %7 offset:1056"
                : "=&v"(sv1A), "=&v"(sv1B), "=&v"(RA0), "=&v"(RA1),
                  "=&v"(RA2), "=&v"(RA3)
                : "v"(sva_), "v"(vaBase) : "memory");
        }
        int c = 0;
        for (; c + 1 < nc; c += 2) {
            BODY(c,     RA0, RA1, RA2, RA3, RB0, RB1, RB2, RB3,
                 sv1A, sv1B, sv2A, sv2B);
            BODY(c + 1, RB0, RB1, RB2, RB3, RA0, RA1, RA2, RA3,
                 sv2A, sv2B, sv1A, sv1B);
        }
        if (c < nc) {   // final (even) chunk sits in RA
            asm volatile("s_waitcnt lgkmcnt(0)" ::: "memory");
            __builtin_amdgcn_sched_barrier(0);
            const int eb_ = ebase + c * 32;
            f16x8 af_;
#pragma unroll
            for (int j = 0; j < 8; ++j) {
                int m_ = eb_ + (j & 3) + ((j >> 2) << 4);
                af_[j] = ((unsigned)m_ < dd) ? (_Float16)1.0f : (_Float16)0.0f;
            }
            f16x8 bf0_, bf1_;
#pragma unroll
            for (int j = 0; j < 4; ++j) {
                bf0_[j] = RA0[j]; bf0_[j + 4] = RA1[j];
                bf1_[j] = RA2[j]; bf1_[j + 4] = RA3[j];
            }
            acc0 = __builtin_amdgcn_mfma_f32_16x16x32_f16(af_, bf0_, acc0, 0, 0, 0);
            acc1 = __builtin_amdgcn_mfma_f32_16x16x32_f16(af_, bf1_, acc1, 0, 0, 0);
        }
        asm volatile("s_waitcnt vmcnt(0)" ::: "memory");   // drain stage loads
    }
    // epilogue: D row = node-in-group = (lane>>4)*4 + reg, col = lane&15
    const int nl0 = (lane >> 4) << 2;
#pragma unroll
    for (int r2 = 0; r2 < 4; ++r2) {
        const int node = nb + nl0 + r2;
        const float di = dinv[node];
        const float s0 = __half2float(tq[(size_t)node * QF + col]);
        const float s1 = __half2float(tq[(size_t)node * QF + 16 + col]);
        float v0 = (acc0[r2] + s0) * di;
        float v1 = (acc1[r2] + s1) * di;
        if constexpr (FIRST) {
            v0 += bA[q * QF + col];
            v1 += bA[q * QF + 16 + col];
            _Float16* hp = (_Float16*)(h + (size_t)q * N * QF + (size_t)node * QF);
            __builtin_nontemporal_store((_Float16)fmaxf(v0, 0.f), hp + col);
            __builtin_nontemporal_store((_Float16)fmaxf(v1, 0.f), hp + 16 + col);
        } else {
            const float* bp = (q < 2) ? bA : bB;
            const int fb = (q & 1) * QF;
            v0 += bp[fb + col];
            v1 += bp[fb + 16 + col];
            float* op = (q < 2) ? (out + (size_t)node * F2 + fb)
                                : (out + (size_t)N * F2 + (size_t)node * F2 + fb);
            __builtin_nontemporal_store(v0, op + col);
            __builtin_nontemporal_store(v1, op + 16 + col);
        }
    }
}

extern "C" void kernel_launch(void* const* d_in, const int* in_sizes, int n_in,
                              void* d_out, int out_size, void* d_ws, size_t ws_size,
                              hipStream_t stream) {
    const float* x   = (const float*)d_in[0];
    const int*   ei  = (const int*)d_in[1];
    const float* W1  = (const float*)d_in[3];
    const float* b1  = (const float*)d_in[4];
    const float* Wmu = (const float*)d_in[5];
    const float* bmu = (const float*)d_in[6];
    const float* Wls = (const float*)d_in[7];
    const float* bls = (const float*)d_in[8];

    const int N = in_sizes[0] / IN_DIM;
    const int E = in_sizes[1] / 2;
    const int* src = ei;
    const int* dst = ei + E;
    float* out = (float*)d_out;

    // ---- workspace carve (units: 4B slots) ----
    size_t off = 0;
    auto carve = [&](size_t n) { size_t o = off; off += (n + 3) & ~(size_t)3; return o; };
    float* ws = (float*)d_ws;
    float*  dinv   =        ws + carve(N);
    int*    rs     = (int*)(ws + carve(N));
    int*    re     = (int*)(ws + carve(N));
    int*    cnt    = (int*)(ws + carve(N));
    int*    cur    = (int*)(ws + carve(N));
    int*    bsum   = (int*)(ws + carve(64));
    ushort* ssrc   = (ushort*)(ws + carve(((size_t)E + 1024) / 2 + 4));
    __half* t16    = (__half*)(ws + carve((size_t)N * F1 / 2));  // [4][N][32]
    __half* h16    = (__half*)(ws + carve((size_t)N * F1 / 2));  // [4][N][32]
    __half* W1frag = (__half*)(ws + carve(8 * 8 * 64 * 8 / 2));
    __half* Wcfrag = (__half*)(ws + carve(4 * 8 * 64 * 8 / 2));
    (void)ws_size;
    __half* t2_16 = t16;   // GEMM2 output reuses t16 (dead after gather1)

    k_prep_frags<<<cdiv_i(8 * 8 * 64 + 4 * 8 * 64, 256), 256, 0, stream>>>(
        W1, Wmu, Wls, W1frag, Wcfrag);

    // CSR build: hist -> scan(2-level) -> finalize -> scatter
    const int NT = cdiv_i(N, 1024);        // 49 scan tiles (<=64)
    hipMemsetAsync(cnt, 0, sizeof(int) * N, stream);
    k_hist<<<cdiv_i(E, 4096), 512, 0, stream>>>(dst, cnt, E);
    k_scan1<<<NT, 1024, 0, stream>>>(cnt, rs, bsum, N);
    k_scan2<<<1, 64, 0, stream>>>(bsum, NT);
    k_fin<<<NT, 1024, 0, stream>>>(cnt, bsum, rs, re, cur, dinv, N);
    k_scatter<<<cdiv_i(E, 4096), 512, 0, stream>>>(src, dst, cur, ssrc, E);

    const int NG = N >> 4;              // 3125 groups of 16 (N % 16 == 0)
    const int NBI = cdiv_i(NG, 8);      // block-octets: grid divisible by 8

    // GEMM1 (MFMA): t16 = fp16(dinv * (x @ W1)), quarter-split layout
    k_gemm1_mfma<<<cdiv_i(N, 64), 256, 0, stream>>>(x, W1frag, dinv, t16, N);
    // conv1 aggregate (pipelined MFMA-gather, XCD-pinned) + bias + relu -> h16
    k_gather_mfma<true><<<8 * NBI, 256, 0, stream>>>(
        rs, re, ssrc, dinv, t16, b1, b1, h16, out, N, NG);
    // GEMM2 (MFMA): t2 = fp16(dinv * (h @ Wcat)), quarter-split
    k_gemm2_mfma<<<cdiv_i(N, 64), 256, 0, stream>>>(h16, Wcfrag, dinv, t2_16, N);
    // conv2 aggregate (pipelined MFMA-gather, XCD-pinned) -> out (mu||logstd)
    k_gather_mfma<false><<<8 * NBI, 256, 0, stream>>>(
        rs, re, ssrc, dinv, t2_16, bmu, bls, h16, out, N, NG);
}